// Round 12
// baseline (195.023 us; speedup 1.0000x reference)
//
#include <hip/hip_runtime.h>
#include <math.h>

#define B_ 8
#define N_ 2048
#define C_ 512
#define K_ 8
#define EPS 1e-6f
#define GENO_RATIO 0.1f

typedef __bf16 bf16x8 __attribute__((ext_vector_type(8)));
typedef float f32x4 __attribute__((ext_vector_type(4)));

__device__ __forceinline__ ushort f2bf(float x) {
    unsigned int u = __float_as_uint(x);
    u += 0x7fffu + ((u >> 16) & 1u);   // RNE (inputs are finite)
    return (ushort)(u >> 16);
}

// ---------------------------------------------------------------------------
// ws layout (float element offsets):
// [64,128)             cnt (int)   [B,K]
// [128,192)            mass        [B,K]
// [192,32960)          hsum        [B,K,C]
// [32960,65728)        ctmp        [B,K,C]
// [65728,196800)       lw          [B,K,N]
// [196800,327872)      ln (int)    [B,K,N]
// [327872,1376448)     w1t2 (bf16) [K][16 cb][512 n][32 cc]   4 MB  (K-tiled)
// [1376448,5570752)    tb2  (bf16) [B][16 cb][2048 n][32 cc]  16.8 MB
// ---------------------------------------------------------------------------

// k_prep: w1 transpose+convert (512 blocks) + zero cnt/mass/hsum/ctmp.
__global__ __launch_bounds__(256) void k_prep(const float* __restrict__ w1,
                                              ushort* __restrict__ w1t2,
                                              float* __restrict__ zws) {
    int id2 = blockIdx.x;
    int tid = threadIdx.x;
    {
        float4 z = {0.f, 0.f, 0.f, 0.f};
        float4* h4 = (float4*)(zws + 128);     // hsum start (ws+192)
        if (tid < 32) h4[id2 * 32 + tid] = z;
        if (id2 == 0 && tid >= 32 && tid < 64) ((float4*)zws)[tid - 32] = z;
    }
    __shared__ float tile[64][65];
    int k = id2 >> 6;
    int c0 = ((id2 >> 3) & 7) * 64;
    int n0 = (id2 & 7) * 64;
    int tr = tid >> 4;          // 0..15
    int tc4 = (tid & 15) * 4;   // 0..60
    const float* src = w1 + (size_t)k * C_ * C_;
    #pragma unroll
    for (int i = 0; i < 4; ++i) {
        int c = c0 + tr + i * 16;
        float4 v = *(const float4*)(src + (size_t)c * C_ + n0 + tc4);
        tile[tr + i * 16][tc4 + 0] = v.x; tile[tr + i * 16][tc4 + 1] = v.y;
        tile[tr + i * 16][tc4 + 2] = v.z; tile[tr + i * 16][tc4 + 3] = v.w;
    }
    __syncthreads();
    #pragma unroll
    for (int i = 0; i < 4; ++i) {
        int rr = tr + i * 16;
        int n = n0 + rr;
        int c = c0 + tc4;
        int cb = c >> 5, cc = c & 31;
        uint2 o;
        o.x = (unsigned)f2bf(tile[tc4 + 0][rr]) | ((unsigned)f2bf(tile[tc4 + 1][rr]) << 16);
        o.y = (unsigned)f2bf(tile[tc4 + 2][rr]) | ((unsigned)f2bf(tile[tc4 + 3][rr]) << 16);
        *(uint2*)(w1t2 + ((size_t)(k * 16 + cb) * 512 + n) * 32 + cc) = o;
    }
}

// k_gate: gating + bf16 K-tiled token copy + fused list build.
// Block = 4 waves, 64 tokens of one batch (wave wv: 16 tokens). Lane owns 8
// CONTIGUOUS channels (c0=lane*8): vector fp32 loads + one uint4 bf16 store
// per token. Gate weights live in 64 VGPRs (loaded once, no LDS conflicts);
// geno logits folded into bias once per wave. List build: wave 0 ballots,
// one global atomicAdd per (block, expert).
__global__ __launch_bounds__(256, 2) void k_gate(const float* __restrict__ tokens,
                                                 const float* __restrict__ gate_w,
                                                 const float* __restrict__ gate_b,
                                                 const float* __restrict__ geno_vec,
                                                 const float* __restrict__ geno_w,
                                                 const float* __restrict__ geno_b,
                                                 int* __restrict__ cnt,
                                                 float* __restrict__ mass,
                                                 int* __restrict__ ln,
                                                 float* __restrict__ lw,
                                                 ushort* __restrict__ tb2) {
    __shared__ int    pks[64];
    __shared__ float2 wts[64];
    int tid = threadIdx.x;
    int wv = tid >> 6, lane = tid & 63;
    int b  = blockIdx.x >> 5;
    int n0 = (blockIdx.x & 31) * 64;
    int p_row = b * 8;
    int c0 = lane * 8;

    // gate weights for rows c0..c0+7 (256B contiguous per lane)
    const float4* gw4 = (const float4*)gate_w;
    float4 gwa[8], gwb[8];
    #pragma unroll
    for (int i = 0; i < 8; ++i) {
        gwa[i] = gw4[(c0 + i) * 2];
        gwb[i] = gw4[(c0 + i) * 2 + 1];
    }
    // geno logits once (depend only on b)
    float ga[8] = {0.f,0.f,0.f,0.f,0.f,0.f,0.f,0.f};
    {
        const float* grow = geno_vec + (size_t)b * C_;
        float4 g0 = *(const float4*)(grow + c0);
        float4 g1 = *(const float4*)(grow + c0 + 4);
        float gvv[8] = {g0.x, g0.y, g0.z, g0.w, g1.x, g1.y, g1.z, g1.w};
        const float4* qw4 = (const float4*)geno_w;
        #pragma unroll
        for (int i = 0; i < 8; ++i) {
            float4 q0 = qw4[(c0 + i) * 2], q1 = qw4[(c0 + i) * 2 + 1];
            ga[0] = fmaf(gvv[i], q0.x, ga[0]); ga[1] = fmaf(gvv[i], q0.y, ga[1]);
            ga[2] = fmaf(gvv[i], q0.z, ga[2]); ga[3] = fmaf(gvv[i], q0.w, ga[3]);
            ga[4] = fmaf(gvv[i], q1.x, ga[4]); ga[5] = fmaf(gvv[i], q1.y, ga[5]);
            ga[6] = fmaf(gvv[i], q1.z, ga[6]); ga[7] = fmaf(gvv[i], q1.w, ga[7]);
        }
        #pragma unroll
        for (int off = 32; off > 0; off >>= 1) {
            #pragma unroll
            for (int j = 0; j < 8; ++j) ga[j] += __shfl_xor(ga[j], off, 64);
        }
    }
    float gbias[8];
    #pragma unroll
    for (int j = 0; j < 8; ++j)
        gbias[j] = gate_b[j] + GENO_RATIO * (ga[j] + geno_b[j]);

    // token loop with distance-1 prefetch
    const float* tb = tokens + ((size_t)(b * N_ + n0 + wv * 16)) * C_ + c0;
    float4 cv0 = *(const float4*)(tb);
    float4 cv1 = *(const float4*)(tb + 4);
    #pragma unroll 1
    for (int it = 0; it < 16; ++it) {
        float4 nv0, nv1;
        if (it < 15) {
            const float* tr2 = tb + (size_t)(it + 1) * C_;
            nv0 = *(const float4*)(tr2);
            nv1 = *(const float4*)(tr2 + 4);
        }
        int n = n0 + wv * 16 + it;
        float tv[8] = {cv0.x, cv0.y, cv0.z, cv0.w, cv1.x, cv1.y, cv1.z, cv1.w};
        float acc[8] = {0.f,0.f,0.f,0.f,0.f,0.f,0.f,0.f};
        #pragma unroll
        for (int i = 0; i < 8; ++i) {
            acc[0] = fmaf(tv[i], gwa[i].x, acc[0]);
            acc[1] = fmaf(tv[i], gwa[i].y, acc[1]);
            acc[2] = fmaf(tv[i], gwa[i].z, acc[2]);
            acc[3] = fmaf(tv[i], gwa[i].w, acc[3]);
            acc[4] = fmaf(tv[i], gwb[i].x, acc[4]);
            acc[5] = fmaf(tv[i], gwb[i].y, acc[5]);
            acc[6] = fmaf(tv[i], gwb[i].z, acc[6]);
            acc[7] = fmaf(tv[i], gwb[i].w, acc[7]);
        }
        // bf16 pack + K-tiled store (8 ch of one 32-chunk -> 16B contiguous)
        {
            int cb = c0 >> 5, cc = c0 & 31;
            uint4 o;
            o.x = (unsigned)f2bf(tv[0]) | ((unsigned)f2bf(tv[1]) << 16);
            o.y = (unsigned)f2bf(tv[2]) | ((unsigned)f2bf(tv[3]) << 16);
            o.z = (unsigned)f2bf(tv[4]) | ((unsigned)f2bf(tv[5]) << 16);
            o.w = (unsigned)f2bf(tv[6]) | ((unsigned)f2bf(tv[7]) << 16);
            *(uint4*)(tb2 + ((size_t)(b * 16 + cb) * 2048 + n) * 32 + cc) = o;
        }
        #pragma unroll
        for (int off = 32; off > 0; off >>= 1) {
            #pragma unroll
            for (int j = 0; j < 8; ++j) acc[j] += __shfl_xor(acc[j], off, 64);
        }
        if (lane == 0) {
            float lg[8];
            #pragma unroll
            for (int j = 0; j < 8; ++j) lg[j] = acc[j] + gbias[j];
            int i0 = 0; float v0m = lg[0];
            #pragma unroll
            for (int j = 1; j < 8; ++j) if (lg[j] > v0m) { v0m = lg[j]; i0 = j; }
            int i1 = -1; float v1m = -1e30f;
            #pragma unroll
            for (int j = 0; j < 8; ++j) if (j != i0 && lg[j] > v1m) { v1m = lg[j]; i1 = j; }
            float e = expf(v1m - v0m);
            float w0 = 1.f / (1.f + e);
            float w1s = e / (1.f + e);
            w0 = fmaxf(w0, EPS); w1s = fmaxf(w1s, EPS);
            float s = w0 + w1s; w0 /= s; w1s /= s;
            pks[wv * 16 + it] = i0 | (i1 << 4);
            wts[wv * 16 + it] = make_float2(w0, w1s);
        }
        cv0 = nv0; cv1 = nv1;
    }
    __syncthreads();

    // list build: wave 0, one lane per token of the window
    if (tid < 64) {
        int pk = pks[lane];
        float2 w = wts[lane];
        int n = n0 + lane;
        int i0 = pk & 15, i1 = pk >> 4;
        unsigned long long lt = (1ull << lane) - 1ull;
        #pragma unroll
        for (int kk = 0; kk < 8; ++kk) {
            unsigned long long m0 = __ballot(i0 == kk);
            unsigned long long m1 = __ballot(i1 == kk);
            int c0b = __popcll(m0), c1b = __popcll(m1);
            int base = 0;
            if (lane == 0 && (c0b + c1b) > 0) base = atomicAdd(&cnt[p_row + kk], c0b + c1b);
            base = __shfl(base, 0, 64);
            int pbase = (p_row + kk) * N_;
            if (i0 == kk) {
                int pos = base + __popcll(m0 & lt);
                ln[pbase + pos] = n; lw[pbase + pos] = w.x;
            }
            if (i1 == kk) {
                int pos = base + c0b + __popcll(m1 & lt);
                ln[pbase + pos] = n; lw[pbase + pos] = w.y;
            }
            float s = (i0 == kk ? w.x : 0.f) + (i1 == kk ? w.y : 0.f);
            #pragma unroll
            for (int off = 32; off > 0; off >>= 1) s += __shfl_xor(s, off, 64);
            if (lane == 0 && s != 0.f) atomicAdd(&mass[p_row + kk], s);
        }
    }
}

// grouped GEMM1, MFMA bf16. Grid decode: b = id&7 (XCD affinity),
// m = (id>>3)&31, k = id>>8 (SLOWEST) -> per XCD only ~1 expert slab of w1t2
// is live at a time: working set (2.1 MB tb2 slice + ~0.5 MB slab) fits the
// 4 MB XCD L2, so the 256 MB B re-read stream is served from L2 not L3.
// Wave owns 128 ch (32 MFMA per 8 loads). A: LDS dbuf; B: VGPR dbuf.
__global__ __launch_bounds__(256, 2) void k_ffn1(const ushort* __restrict__ tb2,
                                                 const ushort* __restrict__ w1t2,
                                                 const float* __restrict__ b1,
                                                 const int* __restrict__ cnt,
                                                 const int* __restrict__ ln,
                                                 const float* __restrict__ lw,
                                                 float* __restrict__ hsum) {
    int id = blockIdx.x;
    int b = id & 7, m = (id >> 3) & 31, k = id >> 8;
    int p = b * 8 + k;
    int count = cnt[p];
    int m0 = m * 64;
    if (m0 >= count) return;

    __shared__ ushort As[2][64 * 34];   // 64 rows x 32 bf16, stride 34 (68B)
    __shared__ int   ns_s[64];
    __shared__ float wls_s[64];
    int tid = threadIdx.x;
    if (tid < 64) {
        int mi = m0 + tid;
        bool v = mi < count;
        ns_s[tid]  = v ? ln[p * N_ + mi] : 0;
        wls_s[tid] = v ? lw[p * N_ + mi] : 0.f;
    }
    __syncthreads();

    int wv = tid >> 6, lane = tid & 63;
    int ln15 = lane & 15, q = lane >> 4;

    int r = tid >> 2, q4 = tid & 3;
    const ushort* agbase = tb2 + ((size_t)(b * 16) * 2048 + ns_s[r]) * 32 + q4 * 8;
    const ushort* bb0 = w1t2 + ((size_t)(k * 16) * 512 + wv * 128 + ln15) * 32 + q * 8;

    f32x4 acc[4][8];
    #pragma unroll
    for (int mt = 0; mt < 4; ++mt)
        #pragma unroll
        for (int j = 0; j < 8; ++j) acc[mt][j] = (f32x4){0.f, 0.f, 0.f, 0.f};

    uint4 b_cur[8], b_nxt[8];
    {
        uint4 av = *(const uint4*)(agbase);
        *(uint4*)&As[0][r * 34 + q4 * 8] = av;
    }
    #pragma unroll
    for (int j = 0; j < 8; ++j) b_cur[j] = *(const uint4*)(bb0 + j * 512);
    __syncthreads();

    #pragma unroll 1
    for (int cb = 0; cb < 16; ++cb) {
        uint4 a_nx;
        if (cb < 15) {
            a_nx = *(const uint4*)(agbase + (size_t)(cb + 1) * 65536);
            #pragma unroll
            for (int j = 0; j < 8; ++j)
                b_nxt[j] = *(const uint4*)(bb0 + (size_t)(cb + 1) * 16384 + j * 512);
        }
        const ushort* ab = &As[cb & 1][0];
        bf16x8 afrag[4];
        #pragma unroll
        for (int mt = 0; mt < 4; ++mt)
            afrag[mt] = *(const bf16x8*)(ab + (mt * 16 + ln15) * 34 + q * 8);
        union { uint4 u; bf16x8 v; } bc;
        #pragma unroll
        for (int mt = 0; mt < 4; ++mt)
            #pragma unroll
            for (int j = 0; j < 8; ++j) {
                bc.u = b_cur[j];
                acc[mt][j] = __builtin_amdgcn_mfma_f32_16x16x32_bf16(
                    afrag[mt], bc.v, acc[mt][j], 0, 0, 0);
            }
        if (cb < 15) {
            *(uint4*)&As[(cb + 1) & 1][r * 34 + q4 * 8] = a_nx;
            #pragma unroll
            for (int j = 0; j < 8; ++j) b_cur[j] = b_nxt[j];
        }
        __syncthreads();
    }

    float wrow[4][4];
    #pragma unroll
    for (int mt = 0; mt < 4; ++mt)
        #pragma unroll
        for (int rr = 0; rr < 4; ++rr) wrow[mt][rr] = wls_s[mt * 16 + q * 4 + rr];
    const float* b1k = b1 + k * C_;
    float* hp = hsum + (size_t)p * C_;
    #pragma unroll
    for (int j = 0; j < 8; ++j) {
        int n = wv * 128 + j * 16 + ln15;
        float bias = b1k[n];
        float s = 0.f;
        #pragma unroll
        for (int mt = 0; mt < 4; ++mt)
            #pragma unroll
            for (int rr = 0; rr < 4; ++rr)
                s += wrow[mt][rr] * fmaxf(acc[mt][j][rr] + bias, 0.f);
        s += __shfl_xor(s, 16, 64);
        s += __shfl_xor(s, 32, 64);
        if (q == 0) atomicAdd(&hp[n], s);
    }
}

// combine partials: ctmp[b,k,e] += sum_{c in 64-chunk} hsum[b,k,c]*w2[k,c,e]
__global__ __launch_bounds__(256) void k_comb(const float* __restrict__ hsum,
                                              const float* __restrict__ w2,
                                              float* __restrict__ ctmp) {
    int et = blockIdx.x, k = blockIdx.y, cc = blockIdx.z;
    int e0 = et * 64, c0 = cc * 64;
    __shared__ float hs[8][64];
    int t = threadIdx.x;
    for (int i = t; i < 512; i += 256) {
        int b = i >> 6, c = i & 63;
        hs[b][c] = hsum[(size_t)((b * 8 + k) << 9) + c0 + c];
    }
    __syncthreads();
    int e = e0 + (t & 63); int g = t >> 6;
    float a0 = 0.f, a1 = 0.f;
    const float* w2p = w2 + (size_t)k * C_ * C_ + e;
    #pragma unroll 4
    for (int c = 0; c < 64; ++c) {
        float wv = w2p[(size_t)(c0 + c) * C_];
        a0 = fmaf(hs[g][c], wv, a0);
        a1 = fmaf(hs[g + 4][c], wv, a1);
    }
    atomicAdd(&ctmp[((g * 8 + k) << 9) + e], a0);
    atomicAdd(&ctmp[(((g + 4) * 8 + k) << 9) + e], a1);
}

// finalize: centers = (ctmp + b2*mass)/max(mass,eps); thread0 writes lb_loss
__global__ __launch_bounds__(256) void k_fin(const float* __restrict__ ctmp,
                                             const float* __restrict__ b2,
                                             const float* __restrict__ mass,
                                             const int* __restrict__ cnt,
                                             float* __restrict__ out) {
    int i = blockIdx.x * 256 + threadIdx.x;  // 0..32767
    int b = i >> 12; int ke = i & 4095; int k = ke >> 9;
    float m = mass[b * 8 + k];
    out[i] = (ctmp[i] + b2[ke] * m) / fmaxf(m, EPS);
    if (i == 0) {
        float u[8]; float s = 0.f;
        for (int kk = 0; kk < 8; ++kk) {
            int ck = 0;
            for (int bb = 0; bb < 8; ++bb) ck += cnt[bb * K_ + kk];
            u[kk] = (float)ck / (float)(B_ * N_);
            s += u[kk];
        }
        float mean = s / 8.f;
        float var = 0.f;
        for (int kk = 0; kk < 8; ++kk) { float d = u[kk] - mean; var += d * d; }
        var /= 8.f;
        float denom = mean + EPS;
        out[B_ * K_ * C_] = var / (denom * denom);
    }
}

extern "C" void kernel_launch(void* const* d_in, const int* in_sizes, int n_in,
                              void* d_out, int out_size, void* d_ws, size_t ws_size,
                              hipStream_t stream) {
    (void)in_sizes; (void)n_in; (void)out_size; (void)ws_size;
    const float* tokens   = (const float*)d_in[0];
    const float* geno_vec = (const float*)d_in[1];
    const float* gate_w   = (const float*)d_in[2];
    const float* gate_b   = (const float*)d_in[3];
    const float* geno_w   = (const float*)d_in[4];
    const float* geno_b   = (const float*)d_in[5];
    const float* w1       = (const float*)d_in[6];
    const float* b1       = (const float*)d_in[7];
    const float* w2       = (const float*)d_in[8];
    const float* b2       = (const float*)d_in[9];
    float* out = (float*)d_out;
    float* ws  = (float*)d_ws;

    int*    cnt      = (int*)(ws + 64);          // 64
    float*  mass     = ws + 128;                 // 64
    float*  hsum     = ws + 192;                 // 32768
    float*  ctmp     = ws + 32960;               // 32768
    float*  lw       = ws + 65728;               // 131072
    int*    ln       = (int*)(ws + 196800);      // 131072
    ushort* w1t2     = (ushort*)(ws + 327872);   // 2,097,152 bf16 (4 MB)
    ushort* tb2      = (ushort*)(ws + 1376448);  // 8,388,608 bf16 (16.8 MB)

    k_prep<<<dim3(512), dim3(256), 0, stream>>>(w1, w1t2, ws + 64);
    k_gate<<<dim3(B_ * N_ / 64), dim3(256), 0, stream>>>(tokens, gate_w, gate_b,
                                                         geno_vec, geno_w, geno_b,
                                                         cnt, mass, ln, lw, tb2);
    k_ffn1<<<dim3(B_ * K_ * (N_ / 64)), dim3(256), 0, stream>>>(tb2, w1t2, b1,
                                                                cnt, ln, lw, hsum);
    k_comb<<<dim3(8, K_, 8), dim3(256), 0, stream>>>(hsum, w2, ctmp);
    k_fin<<<dim3(128), dim3(256), 0, stream>>>(ctmp, b2, mass, cnt, out);
}

// Round 13
// 193.105 us; speedup vs baseline: 1.0099x; 1.0099x over previous
//
#include <hip/hip_runtime.h>
#include <math.h>

#define B_ 8
#define N_ 2048
#define C_ 512
#define K_ 8
#define EPS 1e-6f
#define GENO_RATIO 0.1f

typedef __bf16 bf16x8 __attribute__((ext_vector_type(8)));
typedef float f32x4 __attribute__((ext_vector_type(4)));

__device__ __forceinline__ ushort f2bf(float x) {
    unsigned int u = __float_as_uint(x);
    u += 0x7fffu + ((u >> 16) & 1u);   // RNE (inputs are finite)
    return (ushort)(u >> 16);
}

// ---------------------------------------------------------------------------
// ws layout (float element offsets):
// [64,128)             cnt (int)   [B,K]
// [128,192)            mass        [B,K]
// [192,32960)          hsum        [B,K,C]
// [32960,65728)        ctmp        [B,K,C]
// [65728,196800)       lw          [B,K,N]
// [196800,327872)      ln (int)    [B,K,N]
// [327872,1376448)     w1t2 (bf16) [K][16 cb][512 n][32 cc]   4 MB  (K-tiled)
// [1376448,5570752)    tb2  (bf16) [B][16 cb][2048 n][32 cc]  16.8 MB
// ---------------------------------------------------------------------------

// k_prep: w1 transpose+convert (512 blocks) + zero cnt/mass/hsum/ctmp.
__global__ __launch_bounds__(256) void k_prep(const float* __restrict__ w1,
                                              ushort* __restrict__ w1t2,
                                              float* __restrict__ zws) {
    int id2 = blockIdx.x;
    int tid = threadIdx.x;
    {
        float4 z = {0.f, 0.f, 0.f, 0.f};
        float4* h4 = (float4*)(zws + 128);     // hsum start (ws+192)
        if (tid < 32) h4[id2 * 32 + tid] = z;
        if (id2 == 0 && tid >= 32 && tid < 64) ((float4*)zws)[tid - 32] = z;
    }
    __shared__ float tile[64][65];
    int k = id2 >> 6;
    int c0 = ((id2 >> 3) & 7) * 64;
    int n0 = (id2 & 7) * 64;
    int tr = tid >> 4;          // 0..15
    int tc4 = (tid & 15) * 4;   // 0..60
    const float* src = w1 + (size_t)k * C_ * C_;
    #pragma unroll
    for (int i = 0; i < 4; ++i) {
        int c = c0 + tr + i * 16;
        float4 v = *(const float4*)(src + (size_t)c * C_ + n0 + tc4);
        tile[tr + i * 16][tc4 + 0] = v.x; tile[tr + i * 16][tc4 + 1] = v.y;
        tile[tr + i * 16][tc4 + 2] = v.z; tile[tr + i * 16][tc4 + 3] = v.w;
    }
    __syncthreads();
    #pragma unroll
    for (int i = 0; i < 4; ++i) {
        int rr = tr + i * 16;
        int n = n0 + rr;
        int c = c0 + tc4;
        int cb = c >> 5, cc = c & 31;
        uint2 o;
        o.x = (unsigned)f2bf(tile[tc4 + 0][rr]) | ((unsigned)f2bf(tile[tc4 + 1][rr]) << 16);
        o.y = (unsigned)f2bf(tile[tc4 + 2][rr]) | ((unsigned)f2bf(tile[tc4 + 3][rr]) << 16);
        *(uint2*)(w1t2 + ((size_t)(k * 16 + cb) * 512 + n) * 32 + cc) = o;
    }
}

// k_gate: gating + bf16 K-tiled token copy + fused list build.
__global__ __launch_bounds__(256, 2) void k_gate(const float* __restrict__ tokens,
                                                 const float* __restrict__ gate_w,
                                                 const float* __restrict__ gate_b,
                                                 const float* __restrict__ geno_vec,
                                                 const float* __restrict__ geno_w,
                                                 const float* __restrict__ geno_b,
                                                 int* __restrict__ cnt,
                                                 float* __restrict__ mass,
                                                 int* __restrict__ ln,
                                                 float* __restrict__ lw,
                                                 ushort* __restrict__ tb2) {
    __shared__ int    pks[64];
    __shared__ float2 wts[64];
    int tid = threadIdx.x;
    int wv = tid >> 6, lane = tid & 63;
    int b  = blockIdx.x >> 5;
    int n0 = (blockIdx.x & 31) * 64;
    int p_row = b * 8;
    int c0 = lane * 8;

    const float4* gw4 = (const float4*)gate_w;
    float4 gwa[8], gwb[8];
    #pragma unroll
    for (int i = 0; i < 8; ++i) {
        gwa[i] = gw4[(c0 + i) * 2];
        gwb[i] = gw4[(c0 + i) * 2 + 1];
    }
    float ga[8] = {0.f,0.f,0.f,0.f,0.f,0.f,0.f,0.f};
    {
        const float* grow = geno_vec + (size_t)b * C_;
        float4 g0 = *(const float4*)(grow + c0);
        float4 g1 = *(const float4*)(grow + c0 + 4);
        float gvv[8] = {g0.x, g0.y, g0.z, g0.w, g1.x, g1.y, g1.z, g1.w};
        const float4* qw4 = (const float4*)geno_w;
        #pragma unroll
        for (int i = 0; i < 8; ++i) {
            float4 q0 = qw4[(c0 + i) * 2], q1 = qw4[(c0 + i) * 2 + 1];
            ga[0] = fmaf(gvv[i], q0.x, ga[0]); ga[1] = fmaf(gvv[i], q0.y, ga[1]);
            ga[2] = fmaf(gvv[i], q0.z, ga[2]); ga[3] = fmaf(gvv[i], q0.w, ga[3]);
            ga[4] = fmaf(gvv[i], q1.x, ga[4]); ga[5] = fmaf(gvv[i], q1.y, ga[5]);
            ga[6] = fmaf(gvv[i], q1.z, ga[6]); ga[7] = fmaf(gvv[i], q1.w, ga[7]);
        }
        #pragma unroll
        for (int off = 32; off > 0; off >>= 1) {
            #pragma unroll
            for (int j = 0; j < 8; ++j) ga[j] += __shfl_xor(ga[j], off, 64);
        }
    }
    float gbias[8];
    #pragma unroll
    for (int j = 0; j < 8; ++j)
        gbias[j] = gate_b[j] + GENO_RATIO * (ga[j] + geno_b[j]);

    const float* tb = tokens + ((size_t)(b * N_ + n0 + wv * 16)) * C_ + c0;
    float4 cv0 = *(const float4*)(tb);
    float4 cv1 = *(const float4*)(tb + 4);
    #pragma unroll 1
    for (int it = 0; it < 16; ++it) {
        float4 nv0, nv1;
        if (it < 15) {
            const float* tr2 = tb + (size_t)(it + 1) * C_;
            nv0 = *(const float4*)(tr2);
            nv1 = *(const float4*)(tr2 + 4);
        }
        int n = n0 + wv * 16 + it;
        float tv[8] = {cv0.x, cv0.y, cv0.z, cv0.w, cv1.x, cv1.y, cv1.z, cv1.w};
        float acc[8] = {0.f,0.f,0.f,0.f,0.f,0.f,0.f,0.f};
        #pragma unroll
        for (int i = 0; i < 8; ++i) {
            acc[0] = fmaf(tv[i], gwa[i].x, acc[0]);
            acc[1] = fmaf(tv[i], gwa[i].y, acc[1]);
            acc[2] = fmaf(tv[i], gwa[i].z, acc[2]);
            acc[3] = fmaf(tv[i], gwa[i].w, acc[3]);
            acc[4] = fmaf(tv[i], gwb[i].x, acc[4]);
            acc[5] = fmaf(tv[i], gwb[i].y, acc[5]);
            acc[6] = fmaf(tv[i], gwb[i].z, acc[6]);
            acc[7] = fmaf(tv[i], gwb[i].w, acc[7]);
        }
        {
            int cb = c0 >> 5, cc = c0 & 31;
            uint4 o;
            o.x = (unsigned)f2bf(tv[0]) | ((unsigned)f2bf(tv[1]) << 16);
            o.y = (unsigned)f2bf(tv[2]) | ((unsigned)f2bf(tv[3]) << 16);
            o.z = (unsigned)f2bf(tv[4]) | ((unsigned)f2bf(tv[5]) << 16);
            o.w = (unsigned)f2bf(tv[6]) | ((unsigned)f2bf(tv[7]) << 16);
            *(uint4*)(tb2 + ((size_t)(b * 16 + cb) * 2048 + n) * 32 + cc) = o;
        }
        #pragma unroll
        for (int off = 32; off > 0; off >>= 1) {
            #pragma unroll
            for (int j = 0; j < 8; ++j) acc[j] += __shfl_xor(acc[j], off, 64);
        }
        if (lane == 0) {
            float lg[8];
            #pragma unroll
            for (int j = 0; j < 8; ++j) lg[j] = acc[j] + gbias[j];
            int i0 = 0; float v0m = lg[0];
            #pragma unroll
            for (int j = 1; j < 8; ++j) if (lg[j] > v0m) { v0m = lg[j]; i0 = j; }
            int i1 = -1; float v1m = -1e30f;
            #pragma unroll
            for (int j = 0; j < 8; ++j) if (j != i0 && lg[j] > v1m) { v1m = lg[j]; i1 = j; }
            float e = expf(v1m - v0m);
            float w0 = 1.f / (1.f + e);
            float w1s = e / (1.f + e);
            w0 = fmaxf(w0, EPS); w1s = fmaxf(w1s, EPS);
            float s = w0 + w1s; w0 /= s; w1s /= s;
            pks[wv * 16 + it] = i0 | (i1 << 4);
            wts[wv * 16 + it] = make_float2(w0, w1s);
        }
        cv0 = nv0; cv1 = nv1;
    }
    __syncthreads();

    if (tid < 64) {
        int pk = pks[lane];
        float2 w = wts[lane];
        int n = n0 + lane;
        int i0 = pk & 15, i1 = pk >> 4;
        unsigned long long lt = (1ull << lane) - 1ull;
        #pragma unroll
        for (int kk = 0; kk < 8; ++kk) {
            unsigned long long m0 = __ballot(i0 == kk);
            unsigned long long m1 = __ballot(i1 == kk);
            int c0b = __popcll(m0), c1b = __popcll(m1);
            int base = 0;
            if (lane == 0 && (c0b + c1b) > 0) base = atomicAdd(&cnt[p_row + kk], c0b + c1b);
            base = __shfl(base, 0, 64);
            int pbase = (p_row + kk) * N_;
            if (i0 == kk) {
                int pos = base + __popcll(m0 & lt);
                ln[pbase + pos] = n; lw[pbase + pos] = w.x;
            }
            if (i1 == kk) {
                int pos = base + c0b + __popcll(m1 & lt);
                ln[pbase + pos] = n; lw[pbase + pos] = w.y;
            }
            float s = (i0 == kk ? w.x : 0.f) + (i1 == kk ? w.y : 0.f);
            #pragma unroll
            for (int off = 32; off > 0; off >>= 1) s += __shfl_xor(s, off, 64);
            if (lane == 0 && s != 0.f) atomicAdd(&mass[p_row + kk], s);
        }
    }
}

// grouped GEMM1, MFMA bf16. Grid decode: k = id&7 -> XCD = k (round-robin
// id%8): each XCD's L2 holds exactly ONE expert's 512 KB w1t2 slab, reused
// from L2 by its 64 active blocks (B is 8x the A traffic — pin B, not A).
// A-gathers now cross-XCD (L3-served, small). m = id>>6: 3/4 of blocks with
// m*64 >= count exit instantly. Wave owns 128 ch; A: LDS dbuf; B: VGPR dbuf.
__global__ __launch_bounds__(256, 2) void k_ffn1(const ushort* __restrict__ tb2,
                                                 const ushort* __restrict__ w1t2,
                                                 const float* __restrict__ b1,
                                                 const int* __restrict__ cnt,
                                                 const int* __restrict__ ln,
                                                 const float* __restrict__ lw,
                                                 float* __restrict__ hsum) {
    int id = blockIdx.x;
    int k = id & 7, b = (id >> 3) & 7, m = id >> 6;
    int p = b * 8 + k;
    int count = cnt[p];
    int m0 = m * 64;
    if (m0 >= count) return;

    __shared__ ushort As[2][64 * 34];   // 64 rows x 32 bf16, stride 34 (68B)
    __shared__ int   ns_s[64];
    __shared__ float wls_s[64];
    int tid = threadIdx.x;
    if (tid < 64) {
        int mi = m0 + tid;
        bool v = mi < count;
        ns_s[tid]  = v ? ln[p * N_ + mi] : 0;
        wls_s[tid] = v ? lw[p * N_ + mi] : 0.f;
    }
    __syncthreads();

    int wv = tid >> 6, lane = tid & 63;
    int ln15 = lane & 15, q = lane >> 4;

    int r = tid >> 2, q4 = tid & 3;
    const ushort* agbase = tb2 + ((size_t)(b * 16) * 2048 + ns_s[r]) * 32 + q4 * 8;
    const ushort* bb0 = w1t2 + ((size_t)(k * 16) * 512 + wv * 128 + ln15) * 32 + q * 8;

    f32x4 acc[4][8];
    #pragma unroll
    for (int mt = 0; mt < 4; ++mt)
        #pragma unroll
        for (int j = 0; j < 8; ++j) acc[mt][j] = (f32x4){0.f, 0.f, 0.f, 0.f};

    uint4 b_cur[8], b_nxt[8];
    {
        uint4 av = *(const uint4*)(agbase);
        *(uint4*)&As[0][r * 34 + q4 * 8] = av;
    }
    #pragma unroll
    for (int j = 0; j < 8; ++j) b_cur[j] = *(const uint4*)(bb0 + j * 512);
    __syncthreads();

    #pragma unroll 1
    for (int cb = 0; cb < 16; ++cb) {
        uint4 a_nx;
        if (cb < 15) {
            a_nx = *(const uint4*)(agbase + (size_t)(cb + 1) * 65536);
            #pragma unroll
            for (int j = 0; j < 8; ++j)
                b_nxt[j] = *(const uint4*)(bb0 + (size_t)(cb + 1) * 16384 + j * 512);
        }
        const ushort* ab = &As[cb & 1][0];
        bf16x8 afrag[4];
        #pragma unroll
        for (int mt = 0; mt < 4; ++mt)
            afrag[mt] = *(const bf16x8*)(ab + (mt * 16 + ln15) * 34 + q * 8);
        union { uint4 u; bf16x8 v; } bc;
        #pragma unroll
        for (int mt = 0; mt < 4; ++mt)
            #pragma unroll
            for (int j = 0; j < 8; ++j) {
                bc.u = b_cur[j];
                acc[mt][j] = __builtin_amdgcn_mfma_f32_16x16x32_bf16(
                    afrag[mt], bc.v, acc[mt][j], 0, 0, 0);
            }
        if (cb < 15) {
            *(uint4*)&As[(cb + 1) & 1][r * 34 + q4 * 8] = a_nx;
            #pragma unroll
            for (int j = 0; j < 8; ++j) b_cur[j] = b_nxt[j];
        }
        __syncthreads();
    }

    float wrow[4][4];
    #pragma unroll
    for (int mt = 0; mt < 4; ++mt)
        #pragma unroll
        for (int rr = 0; rr < 4; ++rr) wrow[mt][rr] = wls_s[mt * 16 + q * 4 + rr];
    const float* b1k = b1 + k * C_;
    float* hp = hsum + (size_t)p * C_;
    #pragma unroll
    for (int j = 0; j < 8; ++j) {
        int n = wv * 128 + j * 16 + ln15;
        float bias = b1k[n];
        float s = 0.f;
        #pragma unroll
        for (int mt = 0; mt < 4; ++mt)
            #pragma unroll
            for (int rr = 0; rr < 4; ++rr)
                s += wrow[mt][rr] * fmaxf(acc[mt][j][rr] + bias, 0.f);
        s += __shfl_xor(s, 16, 64);
        s += __shfl_xor(s, 32, 64);
        if (q == 0) atomicAdd(&hp[n], s);
    }
}

// combine partials: ctmp[b,k,e] += sum_{c in 64-chunk} hsum[b,k,c]*w2[k,c,e]
__global__ __launch_bounds__(256) void k_comb(const float* __restrict__ hsum,
                                              const float* __restrict__ w2,
                                              float* __restrict__ ctmp) {
    int et = blockIdx.x, k = blockIdx.y, cc = blockIdx.z;
    int e0 = et * 64, c0 = cc * 64;
    __shared__ float hs[8][64];
    int t = threadIdx.x;
    for (int i = t; i < 512; i += 256) {
        int b = i >> 6, c = i & 63;
        hs[b][c] = hsum[(size_t)((b * 8 + k) << 9) + c0 + c];
    }
    __syncthreads();
    int e = e0 + (t & 63); int g = t >> 6;
    float a0 = 0.f, a1 = 0.f;
    const float* w2p = w2 + (size_t)k * C_ * C_ + e;
    #pragma unroll 4
    for (int c = 0; c < 64; ++c) {
        float wv = w2p[(size_t)(c0 + c) * C_];
        a0 = fmaf(hs[g][c], wv, a0);
        a1 = fmaf(hs[g + 4][c], wv, a1);
    }
    atomicAdd(&ctmp[((g * 8 + k) << 9) + e], a0);
    atomicAdd(&ctmp[(((g + 4) * 8 + k) << 9) + e], a1);
}

// finalize: centers = (ctmp + b2*mass)/max(mass,eps); thread0 writes lb_loss
__global__ __launch_bounds__(256) void k_fin(const float* __restrict__ ctmp,
                                             const float* __restrict__ b2,
                                             const float* __restrict__ mass,
                                             const int* __restrict__ cnt,
                                             float* __restrict__ out) {
    int i = blockIdx.x * 256 + threadIdx.x;  // 0..32767
    int b = i >> 12; int ke = i & 4095; int k = ke >> 9;
    float m = mass[b * 8 + k];
    out[i] = (ctmp[i] + b2[ke] * m) / fmaxf(m, EPS);
    if (i == 0) {
        float u[8]; float s = 0.f;
        for (int kk = 0; kk < 8; ++kk) {
            int ck = 0;
            for (int bb = 0; bb < 8; ++bb) ck += cnt[bb * K_ + kk];
            u[kk] = (float)ck / (float)(B_ * N_);
            s += u[kk];
        }
        float mean = s / 8.f;
        float var = 0.f;
        for (int kk = 0; kk < 8; ++kk) { float d = u[kk] - mean; var += d * d; }
        var /= 8.f;
        float denom = mean + EPS;
        out[B_ * K_ * C_] = var / (denom * denom);
    }
}

extern "C" void kernel_launch(void* const* d_in, const int* in_sizes, int n_in,
                              void* d_out, int out_size, void* d_ws, size_t ws_size,
                              hipStream_t stream) {
    (void)in_sizes; (void)n_in; (void)out_size; (void)ws_size;
    const float* tokens   = (const float*)d_in[0];
    const float* geno_vec = (const float*)d_in[1];
    const float* gate_w   = (const float*)d_in[2];
    const float* gate_b   = (const float*)d_in[3];
    const float* geno_w   = (const float*)d_in[4];
    const float* geno_b   = (const float*)d_in[5];
    const float* w1       = (const float*)d_in[6];
    const float* b1       = (const float*)d_in[7];
    const float* w2       = (const float*)d_in[8];
    const float* b2       = (const float*)d_in[9];
    float* out = (float*)d_out;
    float* ws  = (float*)d_ws;

    int*    cnt      = (int*)(ws + 64);          // 64
    float*  mass     = ws + 128;                 // 64
    float*  hsum     = ws + 192;                 // 32768
    float*  ctmp     = ws + 32960;               // 32768
    float*  lw       = ws + 65728;               // 131072
    int*    ln       = (int*)(ws + 196800);      // 131072
    ushort* w1t2     = (ushort*)(ws + 327872);   // 2,097,152 bf16 (4 MB)
    ushort* tb2      = (ushort*)(ws + 1376448);  // 8,388,608 bf16 (16.8 MB)

    k_prep<<<dim3(512), dim3(256), 0, stream>>>(w1, w1t2, ws + 64);
    k_gate<<<dim3(B_ * N_ / 64), dim3(256), 0, stream>>>(tokens, gate_w, gate_b,
                                                         geno_vec, geno_w, geno_b,
                                                         cnt, mass, ln, lw, tb2);
    k_ffn1<<<dim3(B_ * K_ * (N_ / 64)), dim3(256), 0, stream>>>(tb2, w1t2, b1,
                                                                cnt, ln, lw, hsum);
    k_comb<<<dim3(8, K_, 8), dim3(256), 0, stream>>>(hsum, w2, ctmp);
    k_fin<<<dim3(128), dim3(256), 0, stream>>>(ctmp, b2, mass, cnt, out);
}